// Round 10
// baseline (118.169 us; speedup 1.0000x reference)
//
#include <hip/hip_runtime.h>
#include <math.h>

#define D_MODEL   2048
#define N_EXPERTS 64
#define TOP_K     8
#define N_TOKENS  16384
#define NTHREADS  512
// ws layout (R2-HW-proven): [kstep 0..63][fr 0..3][ver 0..2][lane 0..63][4 dw]
#define WS_NEED   (64*4*3*64*16)   // 786432 bytes

typedef __attribute__((ext_vector_type(8))) short bf16x8;
typedef __attribute__((ext_vector_type(4))) float f32x4;
typedef __attribute__((ext_vector_type(4))) int   i32x4;

union FragU { i32x4 i; bf16x8 h; };

// exact 3-way truncation split: x == h+m+l + eps, |eps| <= 2^-24 |x|
__device__ __forceinline__ void split3(float x, unsigned &h, unsigned &m, unsigned &l) {
    unsigned ux = __float_as_uint(x);
    h = ux & 0xffff0000u;
    float mf = x - __uint_as_float(h);       // exact (Sterbenz)
    unsigned um = __float_as_uint(mf) & 0xffff0000u;
    float lf = mf - __uint_as_float(um);     // exact
    m = um;
    l = __float_as_uint(lf) & 0xffff0000u;
}

// ---- verbatim from R2 (HW-proven numerics + layout) ----
__global__ __launch_bounds__(256) void pack_w_kernel(const float* __restrict__ gw,
                                                     unsigned* __restrict__ wp) {
    const int g    = blockIdx.x * 256 + threadIdx.x;   // 0..196607
    const int d    = g & 3;
    const int lane = (g >> 2) & 63;
    const int rest = g >> 8;                           // 0..767
    const int v    = rest % 3;
    const int t    = rest / 3;                         // ks*4 + fr
    const int fr   = t & 3;
    const int ks   = t >> 2;
    const int e    = fr * 16 + (lane & 15);            // B col = lane&15
    const int k    = ks * 32 + (lane >> 4) * 8 + 2 * d;
    const float w0 = gw[(size_t)e * D_MODEL + k];
    const float w1 = gw[(size_t)e * D_MODEL + k + 1];
    unsigned h0, m0, l0, h1, m1, l1;
    split3(w0, h0, m0, l0);
    split3(w1, h1, m1, l1);
    const unsigned c0 = (v == 0) ? h0 : ((v == 1) ? m0 : l0);
    const unsigned c1 = (v == 0) ? h1 : ((v == 1) ? m1 : l1);
    wp[g] = (c0 >> 16) | c1;                           // low short = elem0
}

__device__ __forceinline__ void splitpack(const float4 a, const float4 b,
                                          FragU &ph, FragU &pm, FragU &pl) {
    const float f[8] = {a.x, a.y, a.z, a.w, b.x, b.y, b.z, b.w};
#pragma unroll
    for (int d = 0; d < 4; ++d) {
        unsigned h0, m0, l0, h1, m1, l1;
        split3(f[2 * d],     h0, m0, l0);
        split3(f[2 * d + 1], h1, m1, l1);
        ph.i[d] = (int)((h0 >> 16) | h1);
        pm.i[d] = (int)((m0 >> 16) | m1);
        pl.i[d] = (int)((l0 >> 16) | l1);
    }
}

#define MFMA(A_, B_, C_) C_ = __builtin_amdgcn_mfma_f32_16x16x32_bf16((A_).h, (B_).h, C_, 0, 0, 0)

// Geometry for MAX TLP: block = 512 thr = 8 waves = (expert-frag eh:4) x
// (K-half kh:2); 16-token tile; grid = 1024 -> 4 blocks/CU x 8 waves =
// 32 waves/CU = 8 waves/SIMD (HW max). Wave: 1 expert frag, 32 ksteps,
// 3 B-loads + 2 A-loads + 6 MFMA per kstep. VGPR-lean (~50) to fit the
// 64-VGPR cap that 8 waves/SIMD requires. No barriers in the K loop; TLP
// (not ILP) hides the compiler's serialized load waits.
__global__ __launch_bounds__(NTHREADS, 8) void router_mfma(
    const float* __restrict__ x, const unsigned* __restrict__ wp,
    float* __restrict__ out)
{
    // partials: [kh:2][tok:16][expert:64] stride 68 (2-way bank = free)
    __shared__ __align__(16) float part[2 * 1088 + 32];

    const int tid  = threadIdx.x;
    const int lane = tid & 63;
    const int w    = tid >> 6;          // 0..7
    const int eh   = w & 3;             // expert quarter (one 16-wide frag)
    const int kh   = w >> 2;            // K half
    const int m0   = blockIdx.x * 16;

    const int lrow = lane & 15;         // A row / C col
    const int lk   = lane >> 4;         // k-group 0..3

    // A: lane reads x[m0+lrow][kh*1024 + s*32 + lk*8 .. +8]
    const float* xa = x + (size_t)(m0 + lrow) * D_MODEL + kh * 1024 + lk * 8;
    // B: frag fr = eh; dword offset ((ks*4+fr)*3)*256 + lane*4
    const unsigned* wb = wp + (size_t)kh * 32 * 3072 + eh * 768 + lane * 4;

    f32x4 accA = {0.f, 0.f, 0.f, 0.f};
    f32x4 accB = accA;

    // preload A(0)
    float4 Aa = *(const float4*)(xa);
    float4 Ab = *(const float4*)(xa + 4);

    for (int s = 0; s < 32; ++s) {
        // B for this kstep (L2-resident packed weights)
        const unsigned* bt = wb + (size_t)s * 3072;
        const i32x4 Bh = *(const i32x4*)(bt +   0);
        const i32x4 Bm = *(const i32x4*)(bt + 256);
        const i32x4 Bl = *(const i32x4*)(bt + 512);

        // A prefetch for s+1
        float4 Na = Aa, Nb = Ab;
        if (s + 1 < 32) {
            Na = *(const float4*)(xa + (s + 1) * 32);
            Nb = *(const float4*)(xa + (s + 1) * 32 + 4);
        }

        FragU ah, am_, al;
        splitpack(Aa, Ab, ah, am_, al);
        FragU bh, bm, bl;
        bh.i = Bh; bm.i = Bm; bl.i = Bl;

        MFMA(ah, bh, accA);
        MFMA(am_, bh, accA);
        MFMA(al, bh, accA);
        MFMA(ah, bm, accB);
        MFMA(am_, bm, accB);
        MFMA(ah, bl, accB);

        Aa = Na; Ab = Nb;
    }

    // partials: token = lk*4+reg, expert = eh*16 + lrow (R2-HW-proven C layout)
    {
        float* ps = part + kh * 1088;
#pragma unroll
        for (int reg = 0; reg < 4; ++reg)
            ps[(lk * 4 + reg) * 68 + eh * 16 + lrow] = accA[reg] + accB[reg];
    }
    __syncthreads();

    // reduce 2 K-halves: thread j<256 -> (tok=j>>4, e0=(j&15)*4)
    if (tid < 256) {
        const int o = (tid >> 4) * 68 + (tid & 15) * 4;
        float4 s0 = *(const float4*)(part + o);
        float4 s1 = *(const float4*)(part + 1088 + o);
        float4 r = make_float4(s0.x + s1.x, s0.y + s1.y,
                               s0.z + s1.z, s0.w + s1.w);
        *(float4*)(part + o) = r;     // slice 0 becomes lt
    }
    __syncthreads();

    float* lt   = part;               // [tok*68 + e]
    float* smax = part + 2 * 1088;
    float* srs  = smax + 16;

    float* out_idx = out;
    float* out_w   = out + (size_t)N_TOKENS * TOP_K;
    float* out_p   = out + (size_t)2 * N_TOKENS * TOP_K;
    float* out_l   = out_p + (size_t)N_TOKENS * N_EXPERTS;

    if (tid < 16) {
        const int t = tid;
        float tv[TOP_K];
        int   ti[TOP_K];
#pragma unroll
        for (int i = 0; i < TOP_K; ++i) { tv[i] = -INFINITY; ti[i] = 0; }
        float m = -INFINITY;

        for (int e = 0; e < N_EXPERTS; ++e) {
            const float v = lt[t * 68 + e];
            m = fmaxf(m, v);
            if (v > tv[TOP_K - 1]) {
#pragma unroll
                for (int j = TOP_K - 1; j >= 1; --j) {
                    const bool shift = (v > tv[j - 1]);
                    const bool here  = (v > tv[j]);
                    const float ntv = shift ? tv[j - 1] : (here ? v : tv[j]);
                    const int   nti = shift ? ti[j - 1] : (here ? e : ti[j]);
                    tv[j] = ntv; ti[j] = nti;
                }
                if (v > tv[0]) { tv[0] = v; ti[0] = e; }
            }
        }

        float s = 0.f;
        for (int e = 0; e < N_EXPERTS; ++e) s += expf(lt[t * 68 + e] - m);
        const float rs = 1.f / s;
        smax[t] = m;
        srs[t]  = rs;

        float ex[TOP_K];
        float wsum = 0.f;
#pragma unroll
        for (int i = 0; i < TOP_K; ++i) { ex[i] = expf(tv[i] - tv[0]); wsum += ex[i]; }
        const float rw = 1.f / wsum;

        const int tok = m0 + t;
#pragma unroll
        for (int i = 0; i < TOP_K; ++i) {
            out_idx[(size_t)tok * TOP_K + i] = (float)ti[i];
            out_w  [(size_t)tok * TOP_K + i] = ex[i] * rw;
        }
    }
    __syncthreads();

    // 16x64 floats = 256 float4; threads 0..255 write coalesced
    if (tid < 256) {
        const int f = tid * 4;
        const int t = f >> 6;
        const int e = f & 63;
        const float l0 = lt[t * 68 + e + 0];
        const float l1 = lt[t * 68 + e + 1];
        const float l2 = lt[t * 68 + e + 2];
        const float l3 = lt[t * 68 + e + 3];
        const float mm = smax[t];
        const float rr = srs[t];
        float4 pv = make_float4(expf(l0 - mm) * rr, expf(l1 - mm) * rr,
                                expf(l2 - mm) * rr, expf(l3 - mm) * rr);
        float4 lv = make_float4(l0, l1, l2, l3);
        const size_t gbase = (size_t)m0 * N_EXPERTS + f;
        *(float4*)(out_p + gbase) = pv;
        *(float4*)(out_l + gbase) = lv;
    }
}

// ---------------- fallback (R0-proven fp32 path) if ws too small ----------------
__global__ __launch_bounds__(512) void router_fallback(
    const float* __restrict__ x, const float* __restrict__ gw,
    float* __restrict__ out)
{
    __shared__ float xs[64][33];
    __shared__ float wsh[N_EXPERTS][36];
    __shared__ float lt[64][N_EXPERTS + 1];
    __shared__ float smax[64], srs[64];

    const int tid  = threadIdx.x;
    const int lane = tid & 63;
    const int wv   = tid >> 6;
    const int m0   = blockIdx.x * 64;
    const int srow = tid >> 3;
    const int skq  = (tid & 7) * 4;

    const float* xsrc = x  + (size_t)(m0 + srow) * D_MODEL + skq;
    const float* wsrc = gw + (size_t)srow        * D_MODEL + skq;
    float4 xr = *(const float4*)(xsrc);
    float4 wr = *(const float4*)(wsrc);

    float acc[8];
#pragma unroll
    for (int i = 0; i < 8; ++i) acc[i] = 0.f;
    const int e0 = wv * 8;

    for (int c = 0; c < D_MODEL / 32; ++c) {
        xs[srow][skq] = xr.x; xs[srow][skq+1] = xr.y; xs[srow][skq+2] = xr.z; xs[srow][skq+3] = xr.w;
        *(float4*)&wsh[srow][skq] = wr;
        __syncthreads();
        if (c + 1 < D_MODEL / 32) {
            xr = *(const float4*)(xsrc + (c + 1) * 32);
            wr = *(const float4*)(wsrc + (c + 1) * 32);
        }
#pragma unroll 8
        for (int k4 = 0; k4 < 8; ++k4) {
            const float4 xv = *(const float4*)&xs[lane][k4 * 4];
#pragma unroll
            for (int e = 0; e < 8; ++e) {
                const float4 w4 = *(const float4*)&wsh[e0 + e][k4 * 4];
                acc[e] = fmaf(xv.x, w4.x, fmaf(xv.y, w4.y, fmaf(xv.z, w4.z, fmaf(xv.w, w4.w, acc[e]))));
            }
        }
        __syncthreads();
    }
#pragma unroll
    for (int e = 0; e < 8; ++e) lt[lane][e0 + e] = acc[e];
    __syncthreads();

    float* out_idx = out;
    float* out_w   = out + (size_t)N_TOKENS * TOP_K;
    float* out_p   = out + (size_t)2 * N_TOKENS * TOP_K;
    float* out_l   = out_p + (size_t)N_TOKENS * N_EXPERTS;

    if (tid < 64) {
        const int t = tid;
        float tv[TOP_K]; int ti[TOP_K];
#pragma unroll
        for (int i = 0; i < TOP_K; ++i) { tv[i] = -INFINITY; ti[i] = 0; }
        float m = -INFINITY;
        for (int e = 0; e < N_EXPERTS; ++e) {
            const float v = lt[t][e];
            m = fmaxf(m, v);
            if (v > tv[TOP_K - 1]) {
#pragma unroll
                for (int j = TOP_K - 1; j >= 1; --j) {
                    const bool shift = (v > tv[j - 1]);
                    const bool here  = (v > tv[j]);
                    const float ntv = shift ? tv[j - 1] : (here ? v : tv[j]);
                    const int   nti = shift ? ti[j - 1] : (here ? e : ti[j]);
                    tv[j] = ntv; ti[j] = nti;
                }
                if (v > tv[0]) { tv[0] = v; ti[0] = e; }
            }
        }
        float s = 0.f;
        for (int e = 0; e < N_EXPERTS; ++e) s += expf(lt[t][e] - m);
        const float rs = 1.f / s;
        smax[t] = m; srs[t] = rs;
        float ex[TOP_K]; float wsum = 0.f;
#pragma unroll
        for (int i = 0; i < TOP_K; ++i) { ex[i] = expf(tv[i] - tv[0]); wsum += ex[i]; }
        const float rw = 1.f / wsum;
        const int tok = m0 + t;
#pragma unroll
        for (int i = 0; i < TOP_K; ++i) {
            out_idx[(size_t)tok * TOP_K + i] = (float)ti[i];
            out_w  [(size_t)tok * TOP_K + i] = ex[i] * rw;
        }
    }
    __syncthreads();
#pragma unroll
    for (int rep = 0; rep < 2; ++rep) {
        const int f = rep * (512 * 4) + tid * 4;
        const int t = f >> 6;
        const int e = f & 63;
        const float l0 = lt[t][e], l1 = lt[t][e+1], l2 = lt[t][e+2], l3 = lt[t][e+3];
        const float mm = smax[t], rr = srs[t];
        float4 pv = make_float4(expf(l0-mm)*rr, expf(l1-mm)*rr, expf(l2-mm)*rr, expf(l3-mm)*rr);
        float4 lv = make_float4(l0, l1, l2, l3);
        const size_t gbase = (size_t)m0 * N_EXPERTS + f;
        *(float4*)(out_p + gbase) = pv;
        *(float4*)(out_l + gbase) = lv;
    }
}

extern "C" void kernel_launch(void* const* d_in, const int* in_sizes, int n_in,
                              void* d_out, int out_size, void* d_ws, size_t ws_size,
                              hipStream_t stream) {
    const float* x  = (const float*)d_in[0];
    const float* gw = (const float*)d_in[1];
    float* out = (float*)d_out;
    if (ws_size >= (size_t)WS_NEED) {
        unsigned* wp = (unsigned*)d_ws;
        pack_w_kernel<<<dim3(WS_NEED / 4 / 256), dim3(256), 0, stream>>>(gw, wp);
        router_mfma<<<dim3(N_TOKENS / 16), dim3(NTHREADS), 0, stream>>>(x, wp, out);
    } else {
        router_fallback<<<dim3(N_TOKENS / 64), dim3(512), 0, stream>>>(x, gw, out);
    }
}

// Round 12
// 111.505 us; speedup vs baseline: 1.0598x; 1.0598x over previous
//
#include <hip/hip_runtime.h>
#include <math.h>

#define D_MODEL   2048
#define N_EXPERTS 64
#define TOP_K     8
#define N_TOKENS  16384

#define WS_PACK   786432u                     // packed W bytes
#define WS_PART   (8u*16384u*64u*4u)          // 33554432 partial bytes
#define WS_NEED_BIG (WS_PACK + WS_PART)
#define WS_NEED_MID WS_PACK

typedef __attribute__((ext_vector_type(8))) short bf16x8;
typedef __attribute__((ext_vector_type(4))) float f32x4;
typedef __attribute__((ext_vector_type(4))) int   i32x4;

union FragU { i32x4 i; bf16x8 h; };

// exact 3-way truncation split: x == h+m+l + eps, |eps| <= 2^-24 |x|
__device__ __forceinline__ void split3(float x, unsigned &h, unsigned &m, unsigned &l) {
    unsigned ux = __float_as_uint(x);
    h = ux & 0xffff0000u;
    float mf = x - __uint_as_float(h);       // exact (Sterbenz)
    unsigned um = __float_as_uint(mf) & 0xffff0000u;
    float lf = mf - __uint_as_float(um);     // exact
    m = um;
    l = __float_as_uint(lf) & 0xffff0000u;
}

// ---- verbatim from R2 (HW-proven numerics + layout) ----
// ws layout: [kstep 0..63][fr 0..3][ver 0..2][lane 0..63][4 dw]
__global__ __launch_bounds__(256) void pack_w_kernel(const float* __restrict__ gw,
                                                     unsigned* __restrict__ wp) {
    const int g    = blockIdx.x * 256 + threadIdx.x;   // 0..196607
    const int d    = g & 3;
    const int lane = (g >> 2) & 63;
    const int rest = g >> 8;                           // 0..767
    const int v    = rest % 3;
    const int t    = rest / 3;                         // ks*4 + fr
    const int fr   = t & 3;
    const int ks   = t >> 2;
    const int e    = fr * 16 + (lane & 15);            // B col = lane&15
    const int k    = ks * 32 + (lane >> 4) * 8 + 2 * d;
    const float w0 = gw[(size_t)e * D_MODEL + k];
    const float w1 = gw[(size_t)e * D_MODEL + k + 1];
    unsigned h0, m0, l0, h1, m1, l1;
    split3(w0, h0, m0, l0);
    split3(w1, h1, m1, l1);
    const unsigned c0 = (v == 0) ? h0 : ((v == 1) ? m0 : l0);
    const unsigned c1 = (v == 0) ? h1 : ((v == 1) ? m1 : l1);
    wp[g] = (c0 >> 16) | c1;                           // low short = elem0
}

__device__ __forceinline__ void splitpack(const float4 a, const float4 b,
                                          FragU &ph, FragU &pm, FragU &pl) {
    const float f[8] = {a.x, a.y, a.z, a.w, b.x, b.y, b.z, b.w};
#pragma unroll
    for (int d = 0; d < 4; ++d) {
        unsigned h0, m0, l0, h1, m1, l1;
        split3(f[2 * d],     h0, m0, l0);
        split3(f[2 * d + 1], h1, m1, l1);
        ph.i[d] = (int)((h0 >> 16) | h1);
        pm.i[d] = (int)((m0 >> 16) | m1);
        pl.i[d] = (int)((l0 >> 16) | l1);
    }
}

#define MFMA(A_, B_, C_) C_ = __builtin_amdgcn_mfma_f32_16x16x32_bf16((A_).h, (B_).h, C_, 0, 0, 0)

// ======================= K1: weight-stationary GEMM =======================
// grid = 8 kq x 256 token-chunks. Block = 512 thr = 8 waves = 4 expert-frags
// x 2 K-groups. Wave pins W (16 experts x 128 K x 3 planes = 48 VGPR) in
// registers ONCE, then loops 4 token-tiles of 16, loading ONLY A (2 loads per
// kstep). R11 FIX: the two kg waves reduce through LDS (R10 raced on a plain
// global store to the same address); one barrier after the K loop.
__global__ __launch_bounds__(512, 4) void gemm_ws(
    const float* __restrict__ x, const unsigned* __restrict__ wp,
    float* __restrict__ part)
{
    // [kg:2][tok:64][exp:64+pad4] = 34.8 KB; disjoint per-wave regions.
    __shared__ __align__(16) float lds[2][64][68];

    const int tid  = threadIdx.x;
    const int lane = tid & 63;
    const int w    = tid >> 6;       // 0..7
    const int eg   = w & 3;          // expert fragment
    const int kg   = w >> 2;         // K group (0..1)
    const int bx   = blockIdx.x;
    const int tc   = bx & 255;       // token chunk (64 tokens)
    const int kq   = bx >> 8;        // K slice (0..7), 256 floats each

    const int lrow = lane & 15;      // A row / C col
    const int lk   = lane >> 4;      // k-group 0..3

    // ---- resident W: 4 ksteps x 3 planes, loop-invariant (LICM-safe) ----
    const int gk0 = kq * 8 + kg * 4;
    const unsigned* wb = wp + lane * 4;
#define WOFF(j, p) ((size_t)(((gk0 + (j)) * 4 + eg) * 3 + (p)) * 256)
    const i32x4 W0h = *(const i32x4*)(wb + WOFF(0,0));
    const i32x4 W0m = *(const i32x4*)(wb + WOFF(0,1));
    const i32x4 W0l = *(const i32x4*)(wb + WOFF(0,2));
    const i32x4 W1h = *(const i32x4*)(wb + WOFF(1,0));
    const i32x4 W1m = *(const i32x4*)(wb + WOFF(1,1));
    const i32x4 W1l = *(const i32x4*)(wb + WOFF(1,2));
    const i32x4 W2h = *(const i32x4*)(wb + WOFF(2,0));
    const i32x4 W2m = *(const i32x4*)(wb + WOFF(2,1));
    const i32x4 W2l = *(const i32x4*)(wb + WOFF(2,2));
    const i32x4 W3h = *(const i32x4*)(wb + WOFF(3,0));
    const i32x4 W3m = *(const i32x4*)(wb + WOFF(3,1));
    const i32x4 W3l = *(const i32x4*)(wb + WOFF(3,2));
#undef WOFF

    // A base: row tc*64+lrow, col kq*256 + kg*128 + lk*8
    const float* pA = x + (size_t)(tc * 64 + lrow) * D_MODEL
                      + kq * 256 + kg * 128 + lk * 8;

    float4 Ca = *(const float4*)(pA);
    float4 Cb = *(const float4*)(pA + 4);

    for (int tile = 0; tile < 4; ++tile) {
        f32x4 accA = {0.f, 0.f, 0.f, 0.f};
        f32x4 accB = accA;

#define KSTEP(j, WH, WM, WL)                                                 \
        {                                                                    \
            const int nt = ((j) < 3) ? tile : tile + 1;                      \
            const int nj = ((j) + 1) & 3;                                    \
            float4 Na = Ca, Nb = Cb;                                         \
            if (!((tile) == 3 && (j) == 3)) {                                \
                const float* pn = pA + (size_t)nt * 16 * D_MODEL + nj * 32;  \
                Na = *(const float4*)(pn);                                   \
                Nb = *(const float4*)(pn + 4);                               \
            }                                                                \
            FragU ah, am_, al;                                               \
            splitpack(Ca, Cb, ah, am_, al);                                  \
            FragU bh, bm, bl;                                                \
            bh.i = WH; bm.i = WM; bl.i = WL;                                 \
            MFMA(ah, bh, accA); MFMA(am_, bh, accA); MFMA(al, bh, accA);     \
            MFMA(ah, bm, accB); MFMA(am_, bm, accB); MFMA(ah, bl, accB);     \
            Ca = Na; Cb = Nb;                                                \
        }
        KSTEP(0, W0h, W0m, W0l)
        KSTEP(1, W1h, W1m, W1l)
        KSTEP(2, W2h, W2m, W2l)
        KSTEP(3, W3h, W3m, W3l)
#undef KSTEP

        // C layout (R2-HW-proven): tok = tile*16 + lk*4 + reg, exp = eg*16+lrow
#pragma unroll
        for (int reg = 0; reg < 4; ++reg)
            lds[kg][tile * 16 + lk * 4 + reg][eg * 16 + lrow]
                = accA[reg] + accB[reg];
    }
    __syncthreads();

    // cross-kg sum + coalesced float4 store: 1024 float4 / 512 thr = 2 each
    float* pout = part + (size_t)kq * N_TOKENS * 64 + (size_t)(tc * 64) * 64;
#pragma unroll
    for (int it = 0; it < 2; ++it) {
        const int idx = it * 512 + tid;      // 0..1023
        const int tok = idx >> 4;
        const int e4  = (idx & 15) * 4;
        const float4 a = *(const float4*)&lds[0][tok][e4];
        const float4 b = *(const float4*)&lds[1][tok][e4];
        float4 r = make_float4(a.x + b.x, a.y + b.y, a.z + b.z, a.w + b.w);
        *(float4*)(pout + (size_t)tok * 64 + e4) = r;
    }
}

// ======================= K2: reduce partials + epilogue =======================
__global__ __launch_bounds__(256) void reduce_top(
    const float* __restrict__ part, float* __restrict__ out)
{
    __shared__ float lt[16 * 68 + 32];
    const int tid = threadIdx.x;
    const int bx  = blockIdx.x;          // 0..1023 (16 tokens each)
    const int m0  = bx * 16;

    {   // sum 8 K-slice partials: thread -> (tok=tid>>4, 4 experts)
        const int t16 = tid >> 4;
        const int e4  = (tid & 15) * 4;
        const size_t tok = (size_t)m0 + t16;
        float4 s = {0.f, 0.f, 0.f, 0.f};
#pragma unroll
        for (int kq = 0; kq < 8; ++kq) {
            const float4 v = *(const float4*)(part + (size_t)kq * N_TOKENS * 64
                                              + tok * 64 + e4);
            s.x += v.x; s.y += v.y; s.z += v.z; s.w += v.w;
        }
        *(float4*)(&lt[t16 * 68 + e4]) = s;
    }
    __syncthreads();

    float* smax = lt + 16 * 68;
    float* srs  = smax + 16;

    float* out_idx = out;
    float* out_w   = out + (size_t)N_TOKENS * TOP_K;
    float* out_p   = out + (size_t)2 * N_TOKENS * TOP_K;
    float* out_l   = out_p + (size_t)N_TOKENS * N_EXPERTS;

    if (tid < 16) {
        const int t = tid;
        float tv[TOP_K];
        int   ti[TOP_K];
#pragma unroll
        for (int i = 0; i < TOP_K; ++i) { tv[i] = -INFINITY; ti[i] = 0; }
        float m = -INFINITY;

        for (int e = 0; e < N_EXPERTS; ++e) {
            const float v = lt[t * 68 + e];
            m = fmaxf(m, v);
            if (v > tv[TOP_K - 1]) {
#pragma unroll
                for (int j = TOP_K - 1; j >= 1; --j) {
                    const bool shift = (v > tv[j - 1]);
                    const bool here  = (v > tv[j]);
                    const float ntv = shift ? tv[j - 1] : (here ? v : tv[j]);
                    const int   nti = shift ? ti[j - 1] : (here ? e : ti[j]);
                    tv[j] = ntv; ti[j] = nti;
                }
                if (v > tv[0]) { tv[0] = v; ti[0] = e; }
            }
        }

        float s = 0.f;
        for (int e = 0; e < N_EXPERTS; ++e) s += expf(lt[t * 68 + e] - m);
        const float rs = 1.f / s;
        smax[t] = m;
        srs[t]  = rs;

        float ex[TOP_K];
        float wsum = 0.f;
#pragma unroll
        for (int i = 0; i < TOP_K; ++i) { ex[i] = expf(tv[i] - tv[0]); wsum += ex[i]; }
        const float rw = 1.f / wsum;

        const int tok = m0 + t;
#pragma unroll
        for (int i = 0; i < TOP_K; ++i) {
            out_idx[(size_t)tok * TOP_K + i] = (float)ti[i];
            out_w  [(size_t)tok * TOP_K + i] = ex[i] * rw;
        }
    }
    __syncthreads();

    // 16x64 floats = 256 float4, coalesced
    {
        const int f = tid * 4;
        const int t = f >> 6;
        const int e = f & 63;
        const float l0 = lt[t * 68 + e + 0];
        const float l1 = lt[t * 68 + e + 1];
        const float l2 = lt[t * 68 + e + 2];
        const float l3 = lt[t * 68 + e + 3];
        const float mm = smax[t];
        const float rr = srs[t];
        float4 pv = make_float4(expf(l0 - mm) * rr, expf(l1 - mm) * rr,
                                expf(l2 - mm) * rr, expf(l3 - mm) * rr);
        float4 lv = make_float4(l0, l1, l2, l3);
        const size_t gbase = (size_t)m0 * N_EXPERTS + f;
        *(float4*)(out_p + gbase) = pv;
        *(float4*)(out_l + gbase) = lv;
    }
}

// ============ mid-tier fallback: R2's proven kernel (74 µs bench) ============
__global__ __launch_bounds__(512) void router_mfma_mid(
    const float* __restrict__ x, const unsigned* __restrict__ wp,
    float* __restrict__ out)
{
    __shared__ float lt[64][N_EXPERTS + 1];
    __shared__ float smax[64], srs[64];

    const int tid  = threadIdx.x;
    const int lane = tid & 63;
    const int wv   = tid >> 6;
    const int mrow = wv & 1;
    const int ncol = (wv >> 1) & 1;
    const int kh   = wv >> 2;
    const int m0   = blockIdx.x * 64;

    const int lrow = lane & 15;
    const int lk   = lane >> 4;

    const float* xr0 = x + (size_t)(m0 + mrow * 32 + lrow) * D_MODEL + lk * 8;
    const float* xr1 = xr0 + (size_t)16 * D_MODEL;

    f32x4 acc00 = {0.f, 0.f, 0.f, 0.f};
    f32x4 acc01 = acc00, acc10 = acc00, acc11 = acc00;

    const unsigned* wb = wp + (size_t)(ncol * 2 * 3) * 256 + lane * 4;

    int ks = kh;
    float4 A0a = *(const float4*)(xr0 + ks * 32);
    float4 A0b = *(const float4*)(xr0 + ks * 32 + 4);
    float4 A1a = *(const float4*)(xr1 + ks * 32);
    float4 A1b = *(const float4*)(xr1 + ks * 32 + 4);
    const unsigned* bt = wb + ks * 3072;
    i32x4 B0h = *(const i32x4*)(bt +    0);
    i32x4 B0m = *(const i32x4*)(bt +  256);
    i32x4 B0l = *(const i32x4*)(bt +  512);
    i32x4 B1h = *(const i32x4*)(bt +  768);
    i32x4 B1m = *(const i32x4*)(bt + 1024);
    i32x4 B1l = *(const i32x4*)(bt + 1280);

    auto compute = [&](float4 cA0a, float4 cA0b, float4 cA1a, float4 cA1b,
                       i32x4 cB0h, i32x4 cB0m, i32x4 cB0l,
                       i32x4 cB1h, i32x4 cB1m, i32x4 cB1l) {
        FragU a0h, a0m, a0l, a1h, a1m, a1l;
        splitpack(cA0a, cA0b, a0h, a0m, a0l);
        splitpack(cA1a, cA1b, a1h, a1m, a1l);
        FragU b0h, b0m, b0l, b1h, b1m, b1l;
        b0h.i = cB0h; b0m.i = cB0m; b0l.i = cB0l;
        b1h.i = cB1h; b1m.i = cB1m; b1l.i = cB1l;
        MFMA(a0h, b0h, acc00); MFMA(a0h, b0m, acc00); MFMA(a0m, b0h, acc00);
        MFMA(a0h, b0l, acc00); MFMA(a0l, b0h, acc00); MFMA(a0m, b0m, acc00);
        MFMA(a0h, b1h, acc01); MFMA(a0h, b1m, acc01); MFMA(a0m, b1h, acc01);
        MFMA(a0h, b1l, acc01); MFMA(a0l, b1h, acc01); MFMA(a0m, b1m, acc01);
        MFMA(a1h, b0h, acc10); MFMA(a1h, b0m, acc10); MFMA(a1m, b0h, acc10);
        MFMA(a1h, b0l, acc10); MFMA(a1l, b0h, acc10); MFMA(a1m, b0m, acc10);
        MFMA(a1h, b1h, acc11); MFMA(a1h, b1m, acc11); MFMA(a1m, b1h, acc11);
        MFMA(a1h, b1l, acc11); MFMA(a1l, b1h, acc11); MFMA(a1m, b1m, acc11);
    };

    for (int t = 0; t < 31; ++t) {
        const int ks2 = ks + 2;
        float4 N0a = *(const float4*)(xr0 + ks2 * 32);
        float4 N0b = *(const float4*)(xr0 + ks2 * 32 + 4);
        float4 N1a = *(const float4*)(xr1 + ks2 * 32);
        float4 N1b = *(const float4*)(xr1 + ks2 * 32 + 4);
        const unsigned* bt2 = wb + ks2 * 3072;
        i32x4 C0h = *(const i32x4*)(bt2 +    0);
        i32x4 C0m = *(const i32x4*)(bt2 +  256);
        i32x4 C0l = *(const i32x4*)(bt2 +  512);
        i32x4 C1h = *(const i32x4*)(bt2 +  768);
        i32x4 C1m = *(const i32x4*)(bt2 + 1024);
        i32x4 C1l = *(const i32x4*)(bt2 + 1280);

        compute(A0a, A0b, A1a, A1b, B0h, B0m, B0l, B1h, B1m, B1l);

        A0a = N0a; A0b = N0b; A1a = N1a; A1b = N1b;
        B0h = C0h; B0m = C0m; B0l = C0l; B1h = C1h; B1m = C1m; B1l = C1l;
        ks = ks2;
    }
    compute(A0a, A0b, A1a, A1b, B0h, B0m, B0l, B1h, B1m, B1l);

    if (kh == 1) {
#pragma unroll
        for (int r = 0; r < 4; ++r) {
            lt[mrow * 32 +  0 + lk * 4 + r][ncol * 32 +  0 + lrow] = acc00[r];
            lt[mrow * 32 +  0 + lk * 4 + r][ncol * 32 + 16 + lrow] = acc01[r];
            lt[mrow * 32 + 16 + lk * 4 + r][ncol * 32 +  0 + lrow] = acc10[r];
            lt[mrow * 32 + 16 + lk * 4 + r][ncol * 32 + 16 + lrow] = acc11[r];
        }
    }
    __syncthreads();
    if (kh == 0) {
#pragma unroll
        for (int r = 0; r < 4; ++r) {
            lt[mrow * 32 +  0 + lk * 4 + r][ncol * 32 +  0 + lrow] += acc00[r];
            lt[mrow * 32 +  0 + lk * 4 + r][ncol * 32 + 16 + lrow] += acc01[r];
            lt[mrow * 32 + 16 + lk * 4 + r][ncol * 32 +  0 + lrow] += acc10[r];
            lt[mrow * 32 + 16 + lk * 4 + r][ncol * 32 + 16 + lrow] += acc11[r];
        }
    }
    __syncthreads();

    float* out_idx = out;
    float* out_w   = out + (size_t)N_TOKENS * TOP_K;
    float* out_p   = out + (size_t)2 * N_TOKENS * TOP_K;
    float* out_l   = out_p + (size_t)N_TOKENS * N_EXPERTS;

    if (tid < 64) {
        const int t = tid;
        float tv[TOP_K];
        int   ti[TOP_K];
#pragma unroll
        for (int i = 0; i < TOP_K; ++i) { tv[i] = -INFINITY; ti[i] = 0; }
        float m = -INFINITY;
        for (int e = 0; e < N_EXPERTS; ++e) {
            const float v = lt[t][e];
            m = fmaxf(m, v);
            if (v > tv[TOP_K - 1]) {
#pragma unroll
                for (int j = TOP_K - 1; j >= 1; --j) {
                    const bool shift = (v > tv[j - 1]);
                    const bool here  = (v > tv[j]);
                    const float ntv = shift ? tv[j - 1] : (here ? v : tv[j]);
                    const int   nti = shift ? ti[j - 1] : (here ? e : ti[j]);
                    tv[j] = ntv; ti[j] = nti;
                }
                if (v > tv[0]) { tv[0] = v; ti[0] = e; }
            }
        }
        float s = 0.f;
        for (int e = 0; e < N_EXPERTS; ++e) s += expf(lt[t][e] - m);
        const float rs = 1.f / s;
        smax[t] = m; srs[t] = rs;
        float ex[TOP_K]; float wsum = 0.f;
#pragma unroll
        for (int i = 0; i < TOP_K; ++i) { ex[i] = expf(tv[i] - tv[0]); wsum += ex[i]; }
        const float rw = 1.f / wsum;
        const int tok = m0 + t;
#pragma unroll
        for (int i = 0; i < TOP_K; ++i) {
            out_idx[(size_t)tok * TOP_K + i] = (float)ti[i];
            out_w  [(size_t)tok * TOP_K + i] = ex[i] * rw;
        }
    }
    __syncthreads();

#pragma unroll
    for (int rep = 0; rep < 2; ++rep) {
        const int f = rep * (512 * 4) + tid * 4;
        const int t = f >> 6;
        const int e = f & 63;
        const float l0 = lt[t][e + 0];
        const float l1 = lt[t][e + 1];
        const float l2 = lt[t][e + 2];
        const float l3 = lt[t][e + 3];
        const float mm = smax[t];
        const float rr = srs[t];
        float4 pv = make_float4(expf(l0 - mm) * rr, expf(l1 - mm) * rr,
                                expf(l2 - mm) * rr, expf(l3 - mm) * rr);
        float4 lv = make_float4(l0, l1, l2, l3);
        const size_t gbase = (size_t)m0 * N_EXPERTS + f;
        *(float4*)(out_p + gbase) = pv;
        *(float4*)(out_l + gbase) = lv;
    }
}

// ---------------- fallback (R0-proven fp32 path) if ws too small ----------------
__global__ __launch_bounds__(512) void router_fallback(
    const float* __restrict__ x, const float* __restrict__ gw,
    float* __restrict__ out)
{
    __shared__ float xs[64][33];
    __shared__ float wsh[N_EXPERTS][36];
    __shared__ float lt[64][N_EXPERTS + 1];
    __shared__ float smax[64], srs[64];

    const int tid  = threadIdx.x;
    const int lane = tid & 63;
    const int wv   = tid >> 6;
    const int m0   = blockIdx.x * 64;
    const int srow = tid >> 3;
    const int skq  = (tid & 7) * 4;

    const float* xsrc = x  + (size_t)(m0 + srow) * D_MODEL + skq;
    const float* wsrc = gw + (size_t)srow        * D_MODEL + skq;
    float4 xr = *(const float4*)(xsrc);
    float4 wr = *(const float4*)(wsrc);

    float acc[8];
#pragma unroll
    for (int i = 0; i < 8; ++i) acc[i] = 0.f;
    const int e0 = wv * 8;

    for (int c = 0; c < D_MODEL / 32; ++c) {
        xs[srow][skq] = xr.x; xs[srow][skq+1] = xr.y; xs[srow][skq+2] = xr.z; xs[srow][skq+3] = xr.w;
        *(float4*)&wsh[srow][skq] = wr;
        __syncthreads();
        if (c + 1 < D_MODEL / 32) {
            xr = *(const float4*)(xsrc + (c + 1) * 32);
            wr = *(const float4*)(wsrc + (c + 1) * 32);
        }
#pragma unroll 8
        for (int k4 = 0; k4 < 8; ++k4) {
            const float4 xv = *(const float4*)&xs[lane][k4 * 4];
#pragma unroll
            for (int e = 0; e < 8; ++e) {
                const float4 w4 = *(const float4*)&wsh[e0 + e][k4 * 4];
                acc[e] = fmaf(xv.x, w4.x, fmaf(xv.y, w4.y, fmaf(xv.z, w4.z, fmaf(xv.w, w4.w, acc[e]))));
            }
        }
        __syncthreads();
    }
#pragma unroll
    for (int e = 0; e < 8; ++e) lt[lane][e0 + e] = acc[e];
    __syncthreads();

    float* out_idx = out;
    float* out_w   = out + (size_t)N_TOKENS * TOP_K;
    float* out_p   = out + (size_t)2 * N_TOKENS * TOP_K;
    float* out_l   = out_p + (size_t)N_TOKENS * N_EXPERTS;

    if (tid < 64) {
        const int t = tid;
        float tv[TOP_K]; int ti[TOP_K];
#pragma unroll
        for (int i = 0; i < TOP_K; ++i) { tv[i] = -INFINITY; ti[i] = 0; }
        float m = -INFINITY;
        for (int e = 0; e < N_EXPERTS; ++e) {
            const float v = lt[t][e];
            m = fmaxf(m, v);
            if (v > tv[TOP_K - 1]) {
#pragma unroll
                for (int j = TOP_K - 1; j >= 1; --j) {
                    const bool shift = (v > tv[j - 1]);
                    const bool here  = (v > tv[j]);
                    const float ntv = shift ? tv[j - 1] : (here ? v : tv[j]);
                    const int   nti = shift ? ti[j - 1] : (here ? e : ti[j]);
                    tv[j] = ntv; ti[j] = nti;
                }
                if (v > tv[0]) { tv[0] = v; ti[0] = e; }
            }
        }
        float s = 0.f;
        for (int e = 0; e < N_EXPERTS; ++e) s += expf(lt[t][e] - m);
        const float rs = 1.f / s;
        smax[t] = m; srs[t] = rs;
        float ex[TOP_K]; float wsum = 0.f;
#pragma unroll
        for (int i = 0; i < TOP_K; ++i) { ex[i] = expf(tv[i] - tv[0]); wsum += ex[i]; }
        const float rw = 1.f / wsum;
        const int tok = m0 + t;
#pragma unroll
        for (int i = 0; i < TOP_K; ++i) {
            out_idx[(size_t)tok * TOP_K + i] = (float)ti[i];
            out_w  [(size_t)tok * TOP_K + i] = ex[i] * rw;
        }
    }
    __syncthreads();
#pragma unroll
    for (int rep = 0; rep < 2; ++rep) {
        const int f = rep * (512 * 4) + tid * 4;
        const int t = f >> 6;
        const int e = f & 63;
        const float l0 = lt[t][e], l1 = lt[t][e+1], l2 = lt[t][e+2], l3 = lt[t][e+3];
        const float mm = smax[t], rr = srs[t];
        float4 pv = make_float4(expf(l0-mm)*rr, expf(l1-mm)*rr, expf(l2-mm)*rr, expf(l3-mm)*rr);
        float4 lv = make_float4(l0, l1, l2, l3);
        const size_t gbase = (size_t)m0 * N_EXPERTS + f;
        *(float4*)(out_p + gbase) = pv;
        *(float4*)(out_l + gbase) = lv;
    }
}

extern "C" void kernel_launch(void* const* d_in, const int* in_sizes, int n_in,
                              void* d_out, int out_size, void* d_ws, size_t ws_size,
                              hipStream_t stream) {
    const float* x  = (const float*)d_in[0];
    const float* gw = (const float*)d_in[1];
    float* out = (float*)d_out;
    if (ws_size >= (size_t)WS_NEED_BIG) {
        unsigned* wp = (unsigned*)d_ws;
        float* part  = (float*)((char*)d_ws + WS_PACK);
        pack_w_kernel<<<dim3(WS_PACK / 4 / 256), dim3(256), 0, stream>>>(gw, wp);
        gemm_ws<<<dim3(8 * 256), dim3(512), 0, stream>>>(x, wp, part);
        reduce_top<<<dim3(N_TOKENS / 16), dim3(256), 0, stream>>>(part, out);
    } else if (ws_size >= (size_t)WS_NEED_MID) {
        unsigned* wp = (unsigned*)d_ws;
        pack_w_kernel<<<dim3(WS_PACK / 4 / 256), dim3(256), 0, stream>>>(gw, wp);
        router_mfma_mid<<<dim3(N_TOKENS / 64), dim3(512), 0, stream>>>(x, wp, out);
    } else {
        router_fallback<<<dim3(N_TOKENS / 64), dim3(512), 0, stream>>>(x, gw, out);
    }
}